// Round 1
// baseline (1386.207 us; speedup 1.0000x reference)
//
#include <hip/hip_runtime.h>
#include <hip/hip_bf16.h>
#include <stdint.h>

// QuantizedLinear on MI355X (gfx950).
//   C[8192, 11008] = x[8192, 4096] . W^T,  W[n,k] = (q[n,k] - zero[n,g]) * scale[n,g], g = k/128
// Scheme: pre-dequant W -> f16, convert x -> f16, then a single f16 MFMA GEMM
// (m97-style 128x128 tile, BK=64, global_load_lds width=16, 2-barrier K-loop).
// Error budget: f16 rounding of x and w only -> absmax err ~7e-3 vs output absmax ~26.

#define M_DIM 8192
#define K_DIM 4096
#define N_DIM 11008
#define BM 128
#define BN 128
#define BK 64

typedef _Float16 f16x8 __attribute__((ext_vector_type(8)));
typedef float f32x4 __attribute__((ext_vector_type(4)));

// ---------- qweight dtype probe (harness doc says "integer -> const int*",
// reference dtype is int8; detect at runtime from byte pattern) ----------
__device__ __forceinline__ bool q_is_int8(const void* q) {
  // int32-encoded values 0..15: bytes 1..3 of every word are 0.
  // int8-encoded random 0..15: P(48 high bytes all zero) = 16^-48 ~ 0.
  const unsigned* w = (const unsigned*)q;
  unsigned m = 0;
#pragma unroll
  for (int i = 0; i < 16; ++i) m |= w[i] & 0xFFFFFF00u;
  return m != 0u;
}

// ---------- x: fp32 -> f16 ----------
__global__ void cvt_x_kernel(const float* __restrict__ X, _Float16* __restrict__ Xh, long total) {
  long e = ((long)blockIdx.x * blockDim.x + threadIdx.x) * 8;
  const long stride = (long)gridDim.x * blockDim.x * 8;
  for (; e < total; e += stride) {
    const float4 a = *(const float4*)(X + e);
    const float4 b = *(const float4*)(X + e + 4);
    f16x8 o;
    o[0] = (_Float16)a.x; o[1] = (_Float16)a.y; o[2] = (_Float16)a.z; o[3] = (_Float16)a.w;
    o[4] = (_Float16)b.x; o[5] = (_Float16)b.y; o[6] = (_Float16)b.z; o[7] = (_Float16)b.w;
    *(f16x8*)(Xh + e) = o;
  }
}

// ---------- W: groupwise dequant -> f16 [N_DIM][K_DIM] ----------
// flat element e over [O][G][S] maps to (o = e>>12, k = e&4095); scales/zeros index = e>>7.
__global__ void dequant_w_kernel(const void* __restrict__ qraw,
                                 const float* __restrict__ scales,
                                 const float* __restrict__ zeros,
                                 _Float16* __restrict__ W) {
  const bool is8 = q_is_int8(qraw);
  const long total = (long)N_DIM * K_DIM;
  long e = ((long)blockIdx.x * blockDim.x + threadIdx.x) * 8;
  const long stride = (long)gridDim.x * blockDim.x * 8;
  for (; e < total; e += stride) {
    const long g = e >> 7;          // 8 consecutive elems stay in one group (8 | 128)
    const float s = scales[g];
    const float z = zeros[g];
    float v[8];
    if (is8) {
      const uint2 p = *(const uint2*)((const uint8_t*)qraw + e);
      const unsigned a = p.x, b = p.y;
      v[0] = (float)(a & 0xFF);         v[1] = (float)((a >> 8) & 0xFF);
      v[2] = (float)((a >> 16) & 0xFF); v[3] = (float)(a >> 24);
      v[4] = (float)(b & 0xFF);         v[5] = (float)((b >> 8) & 0xFF);
      v[6] = (float)((b >> 16) & 0xFF); v[7] = (float)(b >> 24);
    } else {
      const int* qi = (const int*)qraw;
      const int4 p0 = *(const int4*)(qi + e);
      const int4 p1 = *(const int4*)(qi + e + 4);
      v[0] = (float)p0.x; v[1] = (float)p0.y; v[2] = (float)p0.z; v[3] = (float)p0.w;
      v[4] = (float)p1.x; v[5] = (float)p1.y; v[6] = (float)p1.z; v[7] = (float)p1.w;
    }
    f16x8 o;
#pragma unroll
    for (int k = 0; k < 8; ++k) o[k] = (_Float16)((v[k] - z) * s);
    *(f16x8*)(W + e) = o;
  }
}

// ---------- f16 GEMM: C[M][N] = A[M][K] * B[N][K]^T ----------
// 256 threads = 4 waves (2x2), each wave 64x64 out = 4x4 frags of 16x16x32 f16 MFMA.
// LDS: linear [128][64] f16 tiles for A and B, staged via global_load_lds dwordx4.
__global__ __launch_bounds__(256, 3) void gemm_f16_kernel(
    const _Float16* __restrict__ A, const _Float16* __restrict__ B,
    float* __restrict__ C, int M, int N, int K) {
  __shared__ __align__(16) _Float16 As[BM * BK];
  __shared__ __align__(16) _Float16 Bs[BN * BK];

  const int t = threadIdx.x;
  const int bm = blockIdx.x, bn = blockIdx.y;
  const int w = t >> 6, l = t & 63;
  const int wrO = (w >> 1) * 64;   // wave row origin in tile
  const int wcO = (w & 1) * 64;    // wave col origin in tile
  const int fr = l & 15;           // fragment row/col index
  const int kg = (l >> 4) * 8;     // per-lane k offset within K=32 step

  f32x4 acc[4][4] = {};

  // staging: thread t loads 16B; LDS flat halfword off = j*2048 + t*8
  // -> row r = j*32 + t/8, col elem = (t&7)*8 (linear layout matches
  //    global_load_lds's wave-uniform-base + lane*16 write rule)
  const int r0 = t >> 3;
  const int ce = (t & 7) * 8;
  const _Float16* Ag = A + (size_t)(bm * BM + r0) * K + ce;
  const _Float16* Bg = B + (size_t)(bn * BN + r0) * K + ce;

  for (int kt = 0; kt < K; kt += BK) {
#pragma unroll
    for (int j = 0; j < 4; ++j) {
      __builtin_amdgcn_global_load_lds(
          (const __attribute__((address_space(1))) void*)(Ag + (size_t)(j * 32) * K + kt),
          (__attribute__((address_space(3))) void*)(As + j * 2048 + t * 8), 16, 0, 0);
      __builtin_amdgcn_global_load_lds(
          (const __attribute__((address_space(1))) void*)(Bg + (size_t)(j * 32) * K + kt),
          (__attribute__((address_space(3))) void*)(Bs + j * 2048 + t * 8), 16, 0, 0);
    }
    __syncthreads();   // compiler drains vmcnt before s_barrier (known m97 behavior)

#pragma unroll
    for (int kk = 0; kk < 2; ++kk) {
      f16x8 af[4], bf[4];
#pragma unroll
      for (int i = 0; i < 4; ++i)
        af[i] = *(const f16x8*)(As + (wrO + i * 16 + fr) * BK + kk * 32 + kg);
#pragma unroll
      for (int j = 0; j < 4; ++j)
        bf[j] = *(const f16x8*)(Bs + (wcO + j * 16 + fr) * BK + kk * 32 + kg);
#pragma unroll
      for (int i = 0; i < 4; ++i)
#pragma unroll
        for (int j = 0; j < 4; ++j)
          acc[i][j] = __builtin_amdgcn_mfma_f32_16x16x32_f16(af[i], bf[j], acc[i][j], 0, 0, 0);
    }
    __syncthreads();   // all waves done reading before next stage overwrites
  }

  // C/D layout (m89-verified, dtype-independent): col = lane&15, row = (lane>>4)*4 + reg
  const int qrow = (l >> 4) * 4;
  float* Cb = C + (size_t)(bm * BM + wrO + qrow) * N + (bn * BN + wcO + fr);
#pragma unroll
  for (int i = 0; i < 4; ++i)
#pragma unroll
    for (int r = 0; r < 4; ++r) {
      float* Cr = Cb + (size_t)(i * 16 + r) * N;
#pragma unroll
      for (int j = 0; j < 4; ++j) Cr[j * 16] = acc[i][j][r];
    }
}

extern "C" void kernel_launch(void* const* d_in, const int* in_sizes, int n_in,
                              void* d_out, int out_size, void* d_ws, size_t ws_size,
                              hipStream_t stream) {
  const float* x      = (const float*)d_in[0];
  const void*  qw     = d_in[1];                 // int8 or int32 — probed on device
  const float* scales = (const float*)d_in[2];
  const float* zeros  = (const float*)d_in[3];
  float* out = (float*)d_out;

  const size_t xh_bytes = (size_t)M_DIM * K_DIM * sizeof(_Float16); // 64 MiB
  const size_t wh_bytes = (size_t)N_DIM * K_DIM * sizeof(_Float16); // ~86 MiB
  if (ws_size < xh_bytes + wh_bytes) return;  // scratch too small: bail visibly (no corruption)

  _Float16* Xh = (_Float16*)d_ws;
  _Float16* Wh = (_Float16*)((char*)d_ws + xh_bytes);

  cvt_x_kernel<<<2048, 256, 0, stream>>>(x, Xh, (long)M_DIM * K_DIM);
  dequant_w_kernel<<<2048, 256, 0, stream>>>(qw, scales, zeros, Wh);

  dim3 grid(M_DIM / BM, N_DIM / BN);  // 64 x 86, exact
  gemm_f16_kernel<<<grid, 256, 0, stream>>>(Xh, Wh, out, M_DIM, N_DIM, K_DIM);
}

// Round 2
// 1386.172 us; speedup vs baseline: 1.0000x; 1.0000x over previous
//
#include <hip/hip_runtime.h>
#include <hip/hip_bf16.h>
#include <stdint.h>

// QuantizedLinear on MI355X (gfx950).
//   C[8192, 11008] = x[8192, 4096] . W^T,  W[n,k] = (q[n,k] - zero[n,g]) * scale[n,g], g = k/128
// Round 2: pipelined 256x256 GEMM, BK=32, 4-deep LDS ring, counted vmcnt(8)
// (never drain-0 in main loop), raw s_barrier, setprio around MFMA, XCD swizzle.

#define M_DIM 8192
#define K_DIM 4096
#define N_DIM 11008

typedef _Float16 f16x8 __attribute__((ext_vector_type(8)));
typedef float f32x4 __attribute__((ext_vector_type(4)));

// ---------- qweight dtype probe (int8 vs int32 encoding) ----------
__device__ __forceinline__ bool q_is_int8(const void* q) {
  const unsigned* w = (const unsigned*)q;
  unsigned m = 0;
#pragma unroll
  for (int i = 0; i < 16; ++i) m |= w[i] & 0xFFFFFF00u;
  return m != 0u;
}

// ---------- x: fp32 -> f16 ----------
__global__ void cvt_x_kernel(const float* __restrict__ X, _Float16* __restrict__ Xh, long total) {
  long e = ((long)blockIdx.x * blockDim.x + threadIdx.x) * 8;
  const long stride = (long)gridDim.x * blockDim.x * 8;
  for (; e < total; e += stride) {
    const float4 a = *(const float4*)(X + e);
    const float4 b = *(const float4*)(X + e + 4);
    f16x8 o;
    o[0] = (_Float16)a.x; o[1] = (_Float16)a.y; o[2] = (_Float16)a.z; o[3] = (_Float16)a.w;
    o[4] = (_Float16)b.x; o[5] = (_Float16)b.y; o[6] = (_Float16)b.z; o[7] = (_Float16)b.w;
    *(f16x8*)(Xh + e) = o;
  }
}

// ---------- W: groupwise dequant -> f16 [N_DIM][K_DIM] ----------
__global__ void dequant_w_kernel(const void* __restrict__ qraw,
                                 const float* __restrict__ scales,
                                 const float* __restrict__ zeros,
                                 _Float16* __restrict__ W) {
  const bool is8 = q_is_int8(qraw);
  const long total = (long)N_DIM * K_DIM;
  long e = ((long)blockIdx.x * blockDim.x + threadIdx.x) * 8;
  const long stride = (long)gridDim.x * blockDim.x * 8;
  for (; e < total; e += stride) {
    const long g = e >> 7;
    const float s = scales[g];
    const float z = zeros[g];
    float v[8];
    if (is8) {
      const uint2 p = *(const uint2*)((const uint8_t*)qraw + e);
      const unsigned a = p.x, b = p.y;
      v[0] = (float)(a & 0xFF);         v[1] = (float)((a >> 8) & 0xFF);
      v[2] = (float)((a >> 16) & 0xFF); v[3] = (float)(a >> 24);
      v[4] = (float)(b & 0xFF);         v[5] = (float)((b >> 8) & 0xFF);
      v[6] = (float)((b >> 16) & 0xFF); v[7] = (float)(b >> 24);
    } else {
      const int* qi = (const int*)qraw;
      const int4 p0 = *(const int4*)(qi + e);
      const int4 p1 = *(const int4*)(qi + e + 4);
      v[0] = (float)p0.x; v[1] = (float)p0.y; v[2] = (float)p0.z; v[3] = (float)p0.w;
      v[4] = (float)p1.x; v[5] = (float)p1.y; v[6] = (float)p1.z; v[7] = (float)p1.w;
    }
    f16x8 o;
#pragma unroll
    for (int k = 0; k < 8; ++k) o[k] = (_Float16)((v[k] - z) * s);
    *(f16x8*)(W + e) = o;
  }
}

// ---------- pipelined f16 GEMM: C[M][N] = A[M][K] * B[N][K]^T ----------
// 256x256 tile, BK=32, nt = 4096/32 = 128 K-tiles.
// LDS: 4-buffer ring, As/Bs [4][256*32] f16 = 128 KiB total, LINEAR layout
// ([row][32] f16, 64B row stride -> bank quartet = (row&1)*4 + (lane>>4):
//  uniform 8 lanes/quartet on ds_read_b128, conflict-free, no swizzle needed).
// Pipeline: stage tile t+3 during compute of t; s_waitcnt vmcnt(8) drains only
// tile t+1 (tiles t+2, t+3 = 8 loads stay in flight across the barrier).
__global__ __launch_bounds__(512, 2) void gemm_f16_pipe(
    const _Float16* __restrict__ A, const _Float16* __restrict__ B,
    float* __restrict__ C) {
  __shared__ __align__(16) _Float16 As[4][8192];
  __shared__ __align__(16) _Float16 Bs[4][8192];

  const int t = threadIdx.x;
  // XCD-aware bijective swizzle: 1376 blocks, 1376 % 8 == 0, 172 per XCD.
  // bm-major within a chunk -> 32 consecutive blocks share bn (B-panel = 2 MiB,
  // fits the XCD's 4 MiB L2).
  const int sw = ((blockIdx.x & 7) * 172) + (blockIdx.x >> 3);
  const int bm = sw & 31;   // 0..31  (M tiles)
  const int bn = sw >> 5;   // 0..42  (N tiles)

  const int w = t >> 6, l = t & 63;
  const int wm = w >> 2, wn = w & 3;           // wave grid 2 x 4
  const int fr = l & 15;
  const int cph = (l >> 4) << 3;               // halfword col within BK=32

  // staging: thread t covers 16B at LDS byte t*16 (+ issue*8KiB)
  //   row = issue*128 + t/4, col halfwords = (t&3)*8  (fully linear)
  const int sr = t >> 2;
  const int sc = (t & 3) << 3;
  const _Float16* Ag = A + (size_t)(bm * 256 + sr) * K_DIM + sc;
  const _Float16* Bg = B + (size_t)(bn * 256 + sr) * K_DIM + sc;

  f32x4 acc[8][4] = {};

#define AS1 const __attribute__((address_space(1))) void*
#define AS3 __attribute__((address_space(3))) void*
#define STAGE(kt, bf) do { \
    __builtin_amdgcn_global_load_lds((AS1)(Ag + (kt)), (AS3)(&As[bf][t * 8]), 16, 0, 0); \
    __builtin_amdgcn_global_load_lds((AS1)(Ag + 128 * K_DIM + (kt)), (AS3)(&As[bf][4096 + t * 8]), 16, 0, 0); \
    __builtin_amdgcn_global_load_lds((AS1)(Bg + (kt)), (AS3)(&Bs[bf][t * 8]), 16, 0, 0); \
    __builtin_amdgcn_global_load_lds((AS1)(Bg + 128 * K_DIM + (kt)), (AS3)(&Bs[bf][4096 + t * 8]), 16, 0, 0); \
  } while (0)

#define COMPUTE(bf) do { \
    const _Float16* Ap = &As[bf][(wm * 128 + fr) * 32 + cph]; \
    const _Float16* Bp = &Bs[bf][(wn * 64 + fr) * 32 + cph]; \
    f16x8 af[8]; f16x8 bg[4]; \
    _Pragma("unroll") for (int m = 0; m < 8; ++m) af[m] = *(const f16x8*)(Ap + m * 512); \
    _Pragma("unroll") for (int n = 0; n < 4; ++n) bg[n] = *(const f16x8*)(Bp + n * 512); \
    __builtin_amdgcn_s_setprio(1); \
    _Pragma("unroll") for (int m = 0; m < 8; ++m) \
      _Pragma("unroll") for (int n = 0; n < 4; ++n) \
        acc[m][n] = __builtin_amdgcn_mfma_f32_16x16x32_f16(af[m], bg[n], acc[m][n], 0, 0, 0); \
    __builtin_amdgcn_s_setprio(0); \
  } while (0)

#define WAITV(nimm) asm volatile("s_waitcnt vmcnt(" #nimm ")" ::: "memory")
#define BARRIER() do { __builtin_amdgcn_s_barrier(); asm volatile("" ::: "memory"); } while (0)

  // prologue: tiles 0,1,2 in flight; drain tile 0 only (vmcnt 12 -> 8)
  STAGE(0, 0); STAGE(32, 1); STAGE(64, 2);
  WAITV(8);
  BARRIER();

  int kt = 96;  // tile 3
#pragma unroll 1
  for (int it = 0; it < 31; ++it) {   // K-tiles 0..123, staging 3..126
    STAGE(kt, 3);       COMPUTE(0); WAITV(8); BARRIER();
    STAGE(kt + 32, 0);  COMPUTE(1); WAITV(8); BARRIER();
    STAGE(kt + 64, 1);  COMPUTE(2); WAITV(8); BARRIER();
    STAGE(kt + 96, 2);  COMPUTE(3); WAITV(8); BARRIER();
    kt += 128;
  }
  // K-tile 124: stage last tile (127), then drain the ring
  STAGE(4064, 3); COMPUTE(0); WAITV(8); BARRIER();
  COMPUTE(1); WAITV(4); BARRIER();   // tile 126 landed
  COMPUTE(2); WAITV(0); BARRIER();   // tile 127 landed
  COMPUTE(3);

  // C write: frag (m,n): row = bm*256 + wm*128 + m*16 + (l>>4)*4 + r, col = bn*256 + wn*64 + n*16 + fr
  const int qrow = (l >> 4) * 2;  // note: (l>>4)*4 rows... see below (use *4)
  float* Cb = C + (size_t)(bm * 256 + wm * 128 + (l >> 4) * 4) * N_DIM + bn * 256 + wn * 64 + fr;
  (void)qrow;
#pragma unroll
  for (int m = 0; m < 8; ++m)
#pragma unroll
    for (int r = 0; r < 4; ++r) {
      float* Cr = Cb + (size_t)(m * 16 + r) * N_DIM;
#pragma unroll
      for (int n = 0; n < 4; ++n) Cr[n * 16] = acc[m][n][r];
    }
#undef STAGE
#undef COMPUTE
#undef WAITV
#undef BARRIER
#undef AS1
#undef AS3
}

extern "C" void kernel_launch(void* const* d_in, const int* in_sizes, int n_in,
                              void* d_out, int out_size, void* d_ws, size_t ws_size,
                              hipStream_t stream) {
  const float* x      = (const float*)d_in[0];
  const void*  qw     = d_in[1];
  const float* scales = (const float*)d_in[2];
  const float* zeros  = (const float*)d_in[3];
  float* out = (float*)d_out;

  const size_t xh_bytes = (size_t)M_DIM * K_DIM * sizeof(_Float16); // 64 MiB
  const size_t wh_bytes = (size_t)N_DIM * K_DIM * sizeof(_Float16); // ~86 MiB
  if (ws_size < xh_bytes + wh_bytes) return;

  _Float16* Xh = (_Float16*)d_ws;
  _Float16* Wh = (_Float16*)((char*)d_ws + xh_bytes);

  cvt_x_kernel<<<2048, 256, 0, stream>>>(x, Xh, (long)M_DIM * K_DIM);
  dequant_w_kernel<<<2048, 256, 0, stream>>>(qw, scales, zeros, Wh);

  gemm_f16_pipe<<<dim3((M_DIM / 256) * (N_DIM / 256)), 512, 0, stream>>>(Xh, Wh, out);
}

// Round 3
// 1280.015 us; speedup vs baseline: 1.0830x; 1.0829x over previous
//
#include <hip/hip_runtime.h>
#include <hip/hip_bf16.h>
#include <stdint.h>

// QuantizedLinear on MI355X (gfx950).
//   C[8192,11008] = x[8192,4096] . W^T,  W[n,k] = (q - zero)*scale, group=128
// Round 3: faithful 8-phase 256x256 BK=64 template (m201-style) in f16.
//  - 8 waves (2M x 4N), per-wave 128x64 out, 64 MFMA/K-tile, 16 per phase
//  - LDS 128 KiB: A,B each [2 buf][256][64] f16, XOR swizzle slot^=(row&7)
//    applied as inverse-swizzled GLOBAL source + swizzled ds_read (linear
//    global_load_lds dest, rule #21)
//  - counted vmcnt(4) at phases 4 and 8 only; raw s_barrier; setprio on MFMA
// Staging schedule (iter i computes T0=2i from buf0 in ph1-4, T1=2i+1 from
// buf1 in ph5-8; A halves of a buf are read ph1-4(5-8), B halves ph1-2(5-6)):
//   ph1: stage A(2i+1)->buf1   (A of buf1 last read ph8 prev iter)
//   ph3: stage B-lo(2i+2)->buf0 (B of buf0 free after ph2)
//   ph4: stage B-hi(2i+2)->buf0; vmcnt(4)  [=> A(2i+1),B(2i+1) landed for ph5]
//   ph5: stage A(2i+2)->buf0   (A of buf0 free after ph4)
//   ph7: stage B-lo(2i+3)->buf1
//   ph8: stage B-hi(2i+3)->buf1; vmcnt(4)  [=> A(2i+2),B(2i+2) landed for ph1']
// vmcnt(4) = the 4 newest loads (the B pair staged this K-tile) may float.

#define M_DIM 8192
#define K_DIM 4096
#define N_DIM 11008

typedef _Float16 f16x8 __attribute__((ext_vector_type(8)));
typedef float f32x4 __attribute__((ext_vector_type(4)));

// ---------- qweight dtype probe (int8 vs int32 encoding) ----------
__device__ __forceinline__ bool q_is_int8(const void* q) {
  const unsigned* w = (const unsigned*)q;
  unsigned m = 0;
#pragma unroll
  for (int i = 0; i < 16; ++i) m |= w[i] & 0xFFFFFF00u;
  return m != 0u;
}

// ---------- x: fp32 -> f16 ----------
__global__ void cvt_x_kernel(const float* __restrict__ X, _Float16* __restrict__ Xh, long total) {
  long e = ((long)blockIdx.x * blockDim.x + threadIdx.x) * 8;
  const long stride = (long)gridDim.x * blockDim.x * 8;
  for (; e < total; e += stride) {
    const float4 a = *(const float4*)(X + e);
    const float4 b = *(const float4*)(X + e + 4);
    f16x8 o;
    o[0] = (_Float16)a.x; o[1] = (_Float16)a.y; o[2] = (_Float16)a.z; o[3] = (_Float16)a.w;
    o[4] = (_Float16)b.x; o[5] = (_Float16)b.y; o[6] = (_Float16)b.z; o[7] = (_Float16)b.w;
    *(f16x8*)(Xh + e) = o;
  }
}

// ---------- W: groupwise dequant -> f16 [N_DIM][K_DIM] ----------
__global__ void dequant_w_kernel(const void* __restrict__ qraw,
                                 const float* __restrict__ scales,
                                 const float* __restrict__ zeros,
                                 _Float16* __restrict__ W) {
  const bool is8 = q_is_int8(qraw);
  const long total = (long)N_DIM * K_DIM;
  long e = ((long)blockIdx.x * blockDim.x + threadIdx.x) * 8;
  const long stride = (long)gridDim.x * blockDim.x * 8;
  for (; e < total; e += stride) {
    const long g = e >> 7;
    const float s = scales[g];
    const float z = zeros[g];
    float v[8];
    if (is8) {
      const uint2 p = *(const uint2*)((const uint8_t*)qraw + e);
      const unsigned a = p.x, b = p.y;
      v[0] = (float)(a & 0xFF);         v[1] = (float)((a >> 8) & 0xFF);
      v[2] = (float)((a >> 16) & 0xFF); v[3] = (float)(a >> 24);
      v[4] = (float)(b & 0xFF);         v[5] = (float)((b >> 8) & 0xFF);
      v[6] = (float)((b >> 16) & 0xFF); v[7] = (float)(b >> 24);
    } else {
      const int* qi = (const int*)qraw;
      const int4 p0 = *(const int4*)(qi + e);
      const int4 p1 = *(const int4*)(qi + e + 4);
      v[0] = (float)p0.x; v[1] = (float)p0.y; v[2] = (float)p0.z; v[3] = (float)p0.w;
      v[4] = (float)p1.x; v[5] = (float)p1.y; v[6] = (float)p1.z; v[7] = (float)p1.w;
    }
    f16x8 o;
#pragma unroll
    for (int k = 0; k < 8; ++k) o[k] = (_Float16)((v[k] - z) * s);
    *(f16x8*)(W + e) = o;
  }
}

// ---------- 8-phase f16 GEMM ----------
__global__ __launch_bounds__(512, 2) void gemm_f16_8ph(
    const _Float16* __restrict__ A, const _Float16* __restrict__ B,
    float* __restrict__ C) {
  // per buf: [256 rows][8 slots of 8 halfwords] = 32 KiB; 2 bufs A + 2 bufs B = 128 KiB
  __shared__ __align__(16) _Float16 As[2][16384];
  __shared__ __align__(16) _Float16 Bs[2][16384];

  const int t = threadIdx.x;
  // XCD swizzle: 1376 blocks % 8 == 0 -> bijective; 172 per XCD, bm-major.
  const int sw = ((blockIdx.x & 7) * 172) + (blockIdx.x >> 3);
  const int bm = sw & 31;   // 0..31
  const int bn = sw >> 5;   // 0..42

  const int w = t >> 6, l = t & 63;
  const int wm = w >> 2, wn = w & 3;   // wave grid 2 x 4
  const int fr = l & 15;
  const int hi = l >> 4;
  const int sx = fr & 7;               // row&7 for all fragment rows

  // ds_read halfword offsets: row*64 + swizzled_slot*8
  const int sl0 = ((hi) ^ sx) * 8;       // kk=0: unswizzled slot = hi
  const int sl1 = ((4 + hi) ^ sx) * 8;   // kk=1: unswizzled slot = 4+hi
  const int arow = (wm * 128 + fr) * 64;
  const int brow = (wn * 64 + fr) * 64;

  // staging: thread t, inst (h,j): LDS halfword off = h*8192 + j*4096 + t*8
  //   -> row = h*128 + j*64 + (t>>3), linear slot = t&7; row&7 = (t>>3)&7
  //   source slot = (t&7) ^ ((t>>3)&7)  (inverse swizzle on the global side)
  const int tr = t >> 3;
  const int ss = ((t & 7) ^ (tr & 7)) * 8;
  const _Float16* Ag = A + (size_t)(bm * 256 + tr) * K_DIM + ss;
  const _Float16* Bg = B + (size_t)(bn * 256 + tr) * K_DIM + ss;

  f32x4 acc[8][4] = {};
  f16x8 af[4], bg0[4], bg1[4];

#define AS1 const __attribute__((address_space(1))) void*
#define AS3 __attribute__((address_space(3))) void*
#define STAGE_A(b, kt) do { \
    __builtin_amdgcn_global_load_lds((AS1)(Ag + (kt)),                 (AS3)(&As[b][t * 8]), 16, 0, 0); \
    __builtin_amdgcn_global_load_lds((AS1)(Ag +  64 * K_DIM + (kt)),   (AS3)(&As[b][4096 + t * 8]), 16, 0, 0); \
    __builtin_amdgcn_global_load_lds((AS1)(Ag + 128 * K_DIM + (kt)),   (AS3)(&As[b][8192 + t * 8]), 16, 0, 0); \
    __builtin_amdgcn_global_load_lds((AS1)(Ag + 192 * K_DIM + (kt)),   (AS3)(&As[b][12288 + t * 8]), 16, 0, 0); \
  } while (0)
#define STAGE_B_LO(b, kt) do { \
    __builtin_amdgcn_global_load_lds((AS1)(Bg + (kt)),                 (AS3)(&Bs[b][t * 8]), 16, 0, 0); \
    __builtin_amdgcn_global_load_lds((AS1)(Bg +  64 * K_DIM + (kt)),   (AS3)(&Bs[b][4096 + t * 8]), 16, 0, 0); \
  } while (0)
#define STAGE_B_HI(b, kt) do { \
    __builtin_amdgcn_global_load_lds((AS1)(Bg + 128 * K_DIM + (kt)),   (AS3)(&Bs[b][8192 + t * 8]), 16, 0, 0); \
    __builtin_amdgcn_global_load_lds((AS1)(Bg + 192 * K_DIM + (kt)),   (AS3)(&Bs[b][12288 + t * 8]), 16, 0, 0); \
  } while (0)

#define LDA(b, q, sl) do { \
    af[0] = *(const f16x8*)(&As[b][arow + (q) * 4096 + (sl)]); \
    af[1] = *(const f16x8*)(&As[b][arow + (q) * 4096 + 1024 + (sl)]); \
    af[2] = *(const f16x8*)(&As[b][arow + (q) * 4096 + 2048 + (sl)]); \
    af[3] = *(const f16x8*)(&As[b][arow + (q) * 4096 + 3072 + (sl)]); \
  } while (0)
#define LDB(b, dst, sl) do { \
    dst[0] = *(const f16x8*)(&Bs[b][brow + (sl)]); \
    dst[1] = *(const f16x8*)(&Bs[b][brow + 1024 + (sl)]); \
    dst[2] = *(const f16x8*)(&Bs[b][brow + 2048 + (sl)]); \
    dst[3] = *(const f16x8*)(&Bs[b][brow + 3072 + (sl)]); \
  } while (0)

#define MM(q, bgv) do { \
    __builtin_amdgcn_s_setprio(1); \
    _Pragma("unroll") for (int mi = 0; mi < 4; ++mi) \
      _Pragma("unroll") for (int n = 0; n < 4; ++n) \
        acc[(q) * 4 + mi][n] = __builtin_amdgcn_mfma_f32_16x16x32_f16(af[mi], bgv[n], acc[(q) * 4 + mi][n], 0, 0, 0); \
    __builtin_amdgcn_s_setprio(0); \
  } while (0)

#define BAR() do { asm volatile("" ::: "memory"); __builtin_amdgcn_s_barrier(); asm volatile("" ::: "memory"); } while (0)
#define WAITV(n) asm volatile("s_waitcnt vmcnt(" #n ")" ::: "memory")

  // prologue: A(0),B(0)->buf0 [8 loads], B(1)->buf1 [4 loads]; drain first 8.
  STAGE_A(0, 0);
  STAGE_B_LO(0, 0); STAGE_B_HI(0, 0);
  STAGE_B_LO(1, 64); STAGE_B_HI(1, 64);
  WAITV(4);
  BAR();

#pragma unroll 1
  for (int i = 0; i < 32; ++i) {
    const int ktA1 = i * 128 + 64;             // tile 2i+1 (always <= 63)
    const int ktN2 = (i * 128 + 128) & 4095;   // tile 2i+2 (wrap harmless, last iter)
    const int ktN3 = (i * 128 + 192) & 4095;   // tile 2i+3
    // ---- K-tile 2i from buf0 ----
    // ph1: kk0, m0-3
    LDA(0, 0, sl0); LDB(0, bg0, sl0);
    STAGE_A(1, ktA1);
    BAR(); MM(0, bg0); BAR();
    // ph2: kk1, m0-3
    LDA(0, 0, sl1); LDB(0, bg1, sl1);
    BAR(); MM(0, bg1); BAR();
    // ph3: kk0, m4-7
    LDA(0, 1, sl0);
    STAGE_B_LO(0, ktN2);
    BAR(); MM(1, bg0); BAR();
    // ph4: kk1, m4-7
    LDA(0, 1, sl1);
    STAGE_B_HI(0, ktN2);
    BAR(); MM(1, bg1); WAITV(4); BAR();
    // ---- K-tile 2i+1 from buf1 ----
    // ph5
    LDA(1, 0, sl0); LDB(1, bg0, sl0);
    STAGE_A(0, ktN2);
    BAR(); MM(0, bg0); BAR();
    // ph6
    LDA(1, 0, sl1); LDB(1, bg1, sl1);
    BAR(); MM(0, bg1); BAR();
    // ph7
    LDA(1, 1, sl0);
    STAGE_B_LO(1, ktN3);
    BAR(); MM(1, bg0); BAR();
    // ph8
    LDA(1, 1, sl1);
    STAGE_B_HI(1, ktN3);
    BAR(); MM(1, bg1); WAITV(4); BAR();
  }

  // C write: frag (m,n): row = bm*256 + wm*128 + m*16 + hi*4 + r, col = bn*256 + wn*64 + n*16 + fr
  float* Cb = C + (size_t)(bm * 256 + wm * 128 + hi * 4) * N_DIM + bn * 256 + wn * 64 + fr;
#pragma unroll
  for (int m = 0; m < 8; ++m)
#pragma unroll
    for (int r = 0; r < 4; ++r) {
      float* Cr = Cb + (size_t)(m * 16 + r) * N_DIM;
#pragma unroll
      for (int n = 0; n < 4; ++n) Cr[n * 16] = acc[m][n][r];
    }
#undef STAGE_A
#undef STAGE_B_LO
#undef STAGE_B_HI
#undef LDA
#undef LDB
#undef MM
#undef BAR
#undef WAITV
#undef AS1
#undef AS3
}

extern "C" void kernel_launch(void* const* d_in, const int* in_sizes, int n_in,
                              void* d_out, int out_size, void* d_ws, size_t ws_size,
                              hipStream_t stream) {
  const float* x      = (const float*)d_in[0];
  const void*  qw     = d_in[1];
  const float* scales = (const float*)d_in[2];
  const float* zeros  = (const float*)d_in[3];
  float* out = (float*)d_out;

  const size_t xh_bytes = (size_t)M_DIM * K_DIM * sizeof(_Float16); // 64 MiB
  const size_t wh_bytes = (size_t)N_DIM * K_DIM * sizeof(_Float16); // ~86 MiB
  if (ws_size < xh_bytes + wh_bytes) return;

  _Float16* Xh = (_Float16*)d_ws;
  _Float16* Wh = (_Float16*)((char*)d_ws + xh_bytes);

  cvt_x_kernel<<<2048, 256, 0, stream>>>(x, Xh, (long)M_DIM * K_DIM);
  dequant_w_kernel<<<2048, 256, 0, stream>>>(qw, scales, zeros, Wh);

  gemm_f16_8ph<<<dim3((M_DIM / 256) * (N_DIM / 256)), 512, 0, stream>>>(Xh, Wh, out);
}